// Round 3
// baseline (95.273 us; speedup 1.0000x reference)
//
#include <hip/hip_runtime.h>
#include <hip/hip_bf16.h>

#define T_ 2048
#define E_ 768

typedef __attribute__((ext_vector_type(8))) __bf16 bf16x8;
typedef __attribute__((ext_vector_type(8))) unsigned short ushort8;
typedef __attribute__((ext_vector_type(4))) unsigned short ushort4v;
typedef __attribute__((ext_vector_type(4))) float floatx4;

static __device__ __forceinline__ unsigned short f2bf(float f) {
    union { float f; unsigned u; } v; v.f = f;
    unsigned u = v.u;
    u += 0x7FFFu + ((u >> 16) & 1u);   // round-to-nearest-even
    return (unsigned short)(u >> 16);
}

// ---------------- kernel 0: W [768][64] fp32 -> wT [3][64][768] bf16 ----------------
__global__ __launch_bounds__(256) void prep_wT(const float* __restrict__ Wq,
                                               const float* __restrict__ Wk,
                                               const float* __restrict__ Wv,
                                               unsigned short* __restrict__ wT) {
    int w  = blockIdx.x / 12;
    int k0 = (blockIdx.x % 12) * 64;
    const float* W = (w == 0) ? Wq : (w == 1 ? Wk : Wv);
    __shared__ unsigned short sm[64][65];
    int tid = threadIdx.x;
    #pragma unroll
    for (int i = 0; i < 16; ++i) {
        int idx = tid + i * 256;
        int k = idx >> 6, n = idx & 63;
        sm[n][k] = f2bf(W[(size_t)(k0 + k) * 64 + n]);
    }
    __syncthreads();
    #pragma unroll
    for (int i = 0; i < 16; ++i) {
        int idx = tid + i * 256;
        int n = idx >> 6, k = idx & 63;
        wT[(size_t)w * (64 * 768) + (size_t)n * 768 + k0 + k] = sm[n][k];
    }
}

// ---------------- kernel 1: fused QKV projection ----------------
// grid 128, block 256 (4 waves). Block computes 64 rows x 192 cols (Q|K|V).
// x read fp32 ONCE, converted during LDS staging. W fragments direct from L2.
__global__ __launch_bounds__(256) void qkv_proj(const float* __restrict__ x,
                                                const unsigned short* __restrict__ wT,
                                                unsigned short* __restrict__ Qb,
                                                unsigned short* __restrict__ Kb,
                                                unsigned short* __restrict__ vT) {
    int t0 = blockIdx.x * 64;

    __shared__ unsigned short xs[64][72];

    int tid  = threadIdx.x;
    int lane = tid & 63, wv = tid >> 6;
    int r    = tid >> 2, seg = tid & 3;
    int lrow = lane & 15;
    int lk   = (lane >> 4) * 8;
    int qrow4 = (lane >> 4) * 4;

    floatx4 acc[12] = {};

    for (int k0 = 0; k0 < 768; k0 += 64) {
        // stage x (fp32 -> bf16): thread handles 16 contiguous floats
        {
            const float* xp = x + (size_t)(t0 + r) * 768 + k0 + seg * 16;
            float4 a0 = *(const float4*)(xp);
            float4 a1 = *(const float4*)(xp + 4);
            float4 a2 = *(const float4*)(xp + 8);
            float4 a3 = *(const float4*)(xp + 12);
            ushort8 b0, b1;
            b0[0] = f2bf(a0.x); b0[1] = f2bf(a0.y); b0[2] = f2bf(a0.z); b0[3] = f2bf(a0.w);
            b0[4] = f2bf(a1.x); b0[5] = f2bf(a1.y); b0[6] = f2bf(a1.z); b0[7] = f2bf(a1.w);
            b1[0] = f2bf(a2.x); b1[1] = f2bf(a2.y); b1[2] = f2bf(a2.z); b1[3] = f2bf(a2.w);
            b1[4] = f2bf(a3.x); b1[5] = f2bf(a3.y); b1[6] = f2bf(a3.z); b1[7] = f2bf(a3.w);
            *(ushort8*)&xs[r][seg * 16]     = b0;
            *(ushort8*)&xs[r][seg * 16 + 8] = b1;
        }
        __syncthreads();
        #pragma unroll
        for (int kc = 0; kc < 2; ++kc) {
            bf16x8 af = *(const bf16x8*)&xs[wv * 16 + lrow][kc * 32 + lk];
            #pragma unroll
            for (int nf = 0; nf < 12; ++nf) {
                // wT[widx][n][k], widx = nf>>2, n = (nf&3)*16 + lrow
                const unsigned short* wp = wT + (size_t)(nf >> 2) * (64 * 768)
                                              + (size_t)((nf & 3) * 16 + lrow) * 768
                                              + k0 + kc * 32 + lk;
                bf16x8 bfv = *(const bf16x8*)wp;
                acc[nf] = __builtin_amdgcn_mfma_f32_16x16x32_bf16(af, bfv, acc[nf], 0, 0, 0);
            }
        }
        __syncthreads();
    }

    // epilogue: Q scaled into exp2 domain, K plain, V transposed
    const float QS = 0.18033688011112042f;   // 0.125 * log2(e)
    #pragma unroll
    for (int nf = 0; nf < 4; ++nf)
        #pragma unroll
        for (int rg = 0; rg < 4; ++rg) {
            size_t row = (size_t)(t0 + wv * 16 + qrow4 + rg);
            Qb[row * 64 + nf * 16 + lrow] = f2bf(acc[nf][rg] * QS);
        }
    #pragma unroll
    for (int nf = 0; nf < 4; ++nf)
        #pragma unroll
        for (int rg = 0; rg < 4; ++rg) {
            size_t row = (size_t)(t0 + wv * 16 + qrow4 + rg);
            Kb[row * 64 + nf * 16 + lrow] = f2bf(acc[4 + nf][rg]);
        }
    {
        int b  = t0 >> 11;
        int tl = (t0 & 2047) + wv * 16 + qrow4;
        #pragma unroll
        for (int nf = 0; nf < 4; ++nf) {
            int h = nf * 16 + lrow;
            ushort4v pk;
            #pragma unroll
            for (int rg = 0; rg < 4; ++rg) pk[rg] = f2bf(acc[8 + nf][rg]);
            *(ushort4v*)&vT[(size_t)(b * 64 + h) * T_ + tl] = pk;
        }
    }
}

// ---------------- kernel 2: split-KV flash attention, zero barriers ----------------
// grid (8 chunks, 32 qtiles, 4 batch), block 256 (4 independent waves x 16 q-rows).
// K and V read directly from L2 (1 MB each, resident). Only LDS use: per-wave
// P-transpose bounce, double-buffered across tiles (no WAR hazard, no barrier).
__global__ __launch_bounds__(256) void attn_part(const unsigned short* __restrict__ Qb,
                                                 const unsigned short* __restrict__ Kb,
                                                 const unsigned short* __restrict__ vT,
                                                 float* __restrict__ mP,
                                                 float* __restrict__ lP,
                                                 float* __restrict__ oP) {
    int c  = blockIdx.x;
    int qt = blockIdx.y;
    int b  = blockIdx.z;
    int t0 = qt * 64;
    int sBeg = t0 + c * 256;
    if (sBeg >= T_) return;
    int sEnd = sBeg + 256; if (sEnd > T_) sEnd = T_;

    __shared__ unsigned short ps[2][4][16][72];

    int tid  = threadIdx.x;
    int lane = tid & 63, wv = tid >> 6;
    int lrow = lane & 15;
    int lk   = (lane >> 4) * 8;
    int qrow4 = (lane >> 4) * 4;

    bf16x8 qf[2];
    {
        const unsigned short* qp = Qb + (size_t)(b * T_ + t0 + wv * 16 + lrow) * 64 + lk;
        qf[0] = *(const bf16x8*)(qp);
        qf[1] = *(const bf16x8*)(qp + 32);
    }

    float m_[4], l_[4];
    floatx4 of[4] = {};
    #pragma unroll
    for (int rg = 0; rg < 4; ++rg) { m_[rg] = -__builtin_inff(); l_[rg] = 0.f; }

    int buf = 0;
    for (int s0 = sBeg; s0 < sEnd; s0 += 64, buf ^= 1) {
        // S = Q K^T, K fragments straight from L2
        floatx4 sf[4] = {};
        #pragma unroll
        for (int kc = 0; kc < 2; ++kc) {
            bf16x8 af = qf[kc];
            #pragma unroll
            for (int nf = 0; nf < 4; ++nf) {
                const unsigned short* kp = Kb + (size_t)(b * T_ + s0 + nf * 16 + lrow) * 64 + kc * 32 + lk;
                bf16x8 bfv = *(const bf16x8*)kp;
                sf[nf] = __builtin_amdgcn_mfma_f32_16x16x32_bf16(af, bfv, sf[nf], 0, 0, 0);
            }
        }

        if (s0 == t0) {   // diagonal tile: key s < query t -> -inf
            #pragma unroll
            for (int nf = 0; nf < 4; ++nf)
                #pragma unroll
                for (int rg = 0; rg < 4; ++rg) {
                    int sl = nf * 16 + lrow;
                    int ql = wv * 16 + qrow4 + rg;
                    if (sl < ql) sf[nf][rg] = -__builtin_inff();
                }
        }

        float alpha[4];
        #pragma unroll
        for (int rg = 0; rg < 4; ++rg) {
            float v = fmaxf(fmaxf(sf[0][rg], sf[1][rg]), fmaxf(sf[2][rg], sf[3][rg]));
            v = fmaxf(v, __shfl_xor(v, 1, 64));
            v = fmaxf(v, __shfl_xor(v, 2, 64));
            v = fmaxf(v, __shfl_xor(v, 4, 64));
            v = fmaxf(v, __shfl_xor(v, 8, 64));
            float mn = fmaxf(m_[rg], v);
            alpha[rg] = exp2f(m_[rg] - mn);
            m_[rg] = mn;
            l_[rg] *= alpha[rg];
        }

        // P = exp2(S - m); transpose to MFMA-A layout via per-wave LDS bounce
        #pragma unroll
        for (int nf = 0; nf < 4; ++nf)
            #pragma unroll
            for (int rg = 0; rg < 4; ++rg) {
                float p = exp2f(sf[nf][rg] - m_[rg]);
                l_[rg] += p;
                ps[buf][wv][qrow4 + rg][nf * 16 + lrow] = f2bf(p);
            }

        #pragma unroll
        for (int hf = 0; hf < 4; ++hf)
            #pragma unroll
            for (int rg = 0; rg < 4; ++rg)
                of[hf][rg] *= alpha[rg];

        // O += P V, V^T fragments straight from L2
        #pragma unroll
        for (int kc = 0; kc < 2; ++kc) {
            bf16x8 pa = *(const bf16x8*)&ps[buf][wv][lrow][kc * 32 + lk];
            #pragma unroll
            for (int hf = 0; hf < 4; ++hf) {
                const unsigned short* vp = vT + (size_t)(b * 64 + hf * 16 + lrow) * T_ + s0 + kc * 32 + lk;
                bf16x8 vbv = *(const bf16x8*)vp;
                of[hf] = __builtin_amdgcn_mfma_f32_16x16x32_bf16(pa, vbv, of[hf], 0, 0, 0);
            }
        }
    }

    // epilogue: store unnormalized partials
    int p = (b * 32 + qt) * 8 + c;
    #pragma unroll
    for (int rg = 0; rg < 4; ++rg) {
        float v = l_[rg];
        v += __shfl_xor(v, 1, 64);
        v += __shfl_xor(v, 2, 64);
        v += __shfl_xor(v, 4, 64);
        v += __shfl_xor(v, 8, 64);
        l_[rg] = v;
    }
    if (lrow == 0) {
        #pragma unroll
        for (int rg = 0; rg < 4; ++rg) {
            int row = wv * 16 + qrow4 + rg;
            mP[(size_t)p * 64 + row] = m_[rg];
            lP[(size_t)p * 64 + row] = l_[rg];
        }
    }
    #pragma unroll
    for (int hf = 0; hf < 4; ++hf)
        #pragma unroll
        for (int rg = 0; rg < 4; ++rg) {
            int row = wv * 16 + qrow4 + rg;
            oP[((size_t)p * 64 + row) * 64 + hf * 16 + lrow] = of[hf][rg];
        }
}

// ---------------- kernel 3: combine partials ----------------
__global__ __launch_bounds__(256) void combine(const float* __restrict__ mP,
                                               const float* __restrict__ lP,
                                               const float* __restrict__ oP,
                                               float* __restrict__ out) {
    int bq = blockIdx.x >> 2;       // 0..127 = b*32+qt
    int rq = blockIdx.x & 3;
    int qt = bq & 31;
    int b  = bq >> 5;
    int nch = (32 - qt + 3) >> 2;

    int tid = threadIdx.x;
    int r   = rq * 16 + (tid >> 4);
    int cb  = (tid & 15) * 4;

    float M = -__builtin_inff();
    for (int cc = 0; cc < nch; ++cc)
        M = fmaxf(M, mP[(size_t)(bq * 8 + cc) * 64 + r]);

    float L = 0.f;
    float4 o = {0.f, 0.f, 0.f, 0.f};
    for (int cc = 0; cc < nch; ++cc) {
        size_t p = (size_t)(bq * 8 + cc);
        float w = exp2f(mP[p * 64 + r] - M);
        L += lP[p * 64 + r] * w;
        float4 ov = *(const float4*)&oP[(p * 64 + r) * 64 + cb];
        o.x += ov.x * w; o.y += ov.y * w; o.z += ov.z * w; o.w += ov.w * w;
    }
    float inv = 1.0f / L;
    float4 res = {o.x * inv, o.y * inv, o.z * inv, o.w * inv};
    *(float4*)&out[((size_t)(b * T_ + qt * 64 + r)) * 64 + cb] = res;
}

extern "C" void kernel_launch(void* const* d_in, const int* in_sizes, int n_in,
                              void* d_out, int out_size, void* d_ws, size_t ws_size,
                              hipStream_t stream) {
    const float* x  = (const float*)d_in[0];
    const float* Wq = (const float*)d_in[1];
    const float* Wk = (const float*)d_in[2];
    const float* Wv = (const float*)d_in[3];
    float* out = (float*)d_out;

    unsigned short* wT = (unsigned short*)d_ws;       // 288 KB
    unsigned short* Qb = wT + 3 * 64 * 768;           // 1 MB
    unsigned short* Kb = Qb + 8192 * 64;              // 1 MB
    unsigned short* vT = Kb + 8192 * 64;              // 1 MB  [b][h][t]
    float* mP = (float*)(vT + 4 * 64 * T_);           // 256 KB
    float* lP = mP + 1024 * 64;                       // 256 KB
    float* oP = lP + 1024 * 64;                       // 16.75 MB

    prep_wT<<<36, 256, 0, stream>>>(Wq, Wk, Wv, wT);
    qkv_proj<<<128, 256, 0, stream>>>(x, wT, Qb, Kb, vT);
    attn_part<<<dim3(8, 32, 4), 256, 0, stream>>>(Qb, Kb, vT, mP, lP, oP);
    combine<<<512, 256, 0, stream>>>(mP, lP, oP, out);
}

// Round 4
// 65.003 us; speedup vs baseline: 1.4657x; 1.4657x over previous
//
#include <hip/hip_runtime.h>
#include <hip/hip_bf16.h>

#define T_ 2048
#define E_ 768

typedef __attribute__((ext_vector_type(8))) __bf16 bf16x8;
typedef __attribute__((ext_vector_type(8))) unsigned short ushort8;
typedef __attribute__((ext_vector_type(4))) unsigned short ushort4v;
typedef __attribute__((ext_vector_type(4))) float floatx4;

static __device__ __forceinline__ unsigned short f2bf(float f) {
    union { float f; unsigned u; } v; v.f = f;
    unsigned u = v.u;
    u += 0x7FFFu + ((u >> 16) & 1u);   // round-to-nearest-even
    return (unsigned short)(u >> 16);
}

// ---------------- kernel 0: W [768][64] fp32 -> wT [192][768] bf16 (n-major) ----------------
__global__ __launch_bounds__(256) void prep_wT(const float* __restrict__ Wq,
                                               const float* __restrict__ Wk,
                                               const float* __restrict__ Wv,
                                               unsigned short* __restrict__ wT) {
    int w  = blockIdx.x / 12;
    int k0 = (blockIdx.x % 12) * 64;
    const float* W = (w == 0) ? Wq : (w == 1 ? Wk : Wv);
    __shared__ unsigned short sm[64][65];
    int tid = threadIdx.x;
    #pragma unroll
    for (int i = 0; i < 16; ++i) {
        int idx = tid + i * 256;
        int k = idx >> 6, n = idx & 63;
        sm[n][k] = f2bf(W[(size_t)(k0 + k) * 64 + n]);
    }
    __syncthreads();
    #pragma unroll
    for (int i = 0; i < 16; ++i) {
        int idx = tid + i * 256;
        int n = idx >> 6, k = idx & 63;
        wT[(size_t)w * (64 * 768) + (size_t)n * 768 + k0 + k] = sm[n][k];
    }
}

// ---------------- kernel 1: fused QKV projection, no LDS, no barriers ----------------
// grid 512, block 256 (4 independent waves). Wave = 16 rows x 48 cols (3 MFMA frags).
// x A-fragments straight from HBM (fp32->bf16 inline); W B-fragments from L1/L2.
__global__ __launch_bounds__(256) void qkv_proj(const float* __restrict__ x,
                                                const unsigned short* __restrict__ wT,
                                                unsigned short* __restrict__ Qb,
                                                unsigned short* __restrict__ Kb,
                                                unsigned short* __restrict__ vT) {
    int tid  = threadIdx.x;
    int lane = tid & 63, wv = tid >> 6;
    int lrow = lane & 15;
    int kh   = lane >> 4;            // k-eighth selector: 8 elems per group
    int t0   = blockIdx.x * 16;
    int row  = t0 + lrow;
    int n0   = wv * 48;

    const float* xp = x + (size_t)row * 768 + kh * 8;
    const unsigned short* wp[3];
    #pragma unroll
    for (int nf = 0; nf < 3; ++nf)
        wp[nf] = wT + (size_t)(n0 + nf * 16 + lrow) * 768 + kh * 8;

    floatx4 acc[3] = {};

    #pragma unroll 4
    for (int k0 = 0; k0 < 768; k0 += 32) {
        float4 a0 = *(const float4*)(xp + k0);
        float4 a1 = *(const float4*)(xp + k0 + 4);
        bf16x8 af;
        {
            ushort8 t;
            t[0] = f2bf(a0.x); t[1] = f2bf(a0.y); t[2] = f2bf(a0.z); t[3] = f2bf(a0.w);
            t[4] = f2bf(a1.x); t[5] = f2bf(a1.y); t[6] = f2bf(a1.z); t[7] = f2bf(a1.w);
            union { ushort8 u; bf16x8 b; } cv; cv.u = t; af = cv.b;
        }
        #pragma unroll
        for (int nf = 0; nf < 3; ++nf) {
            bf16x8 bfv = *(const bf16x8*)(wp[nf] + k0);
            acc[nf] = __builtin_amdgcn_mfma_f32_16x16x32_bf16(af, bfv, acc[nf], 0, 0, 0);
        }
    }

    // epilogue: C/D layout col = lane&15 (=> n), row m = (lane>>4)*4 + rg (=> t)
    const float QS = 0.18033688011112042f;   // 0.125 * log2(e)
    int mt = t0 + kh * 4;                    // first of 4 consecutive t rows
    #pragma unroll
    for (int nf = 0; nf < 3; ++nf) {
        int nb   = n0 + nf * 16;             // 16-aligned, never straddles a widx boundary
        int widx = nb >> 6;
        int col  = (nb & 63) + lrow;
        if (widx == 0) {
            #pragma unroll
            for (int rg = 0; rg < 4; ++rg)
                Qb[(size_t)(mt + rg) * 64 + col] = f2bf(acc[nf][rg] * QS);
        } else if (widx == 1) {
            #pragma unroll
            for (int rg = 0; rg < 4; ++rg)
                Kb[(size_t)(mt + rg) * 64 + col] = f2bf(acc[nf][rg]);
        } else {
            int b  = mt >> 11;
            int tl = mt & 2047;
            ushort4v pk;
            #pragma unroll
            for (int rg = 0; rg < 4; ++rg) pk[rg] = f2bf(acc[nf][rg]);
            *(ushort4v*)&vT[(size_t)(b * 64 + col) * T_ + tl] = pk;
        }
    }
}

// ---------------- kernel 2: split-KV flash attention (round-2 staged structure) ----------------
// grid (8 chunks, 32 qtiles, 4 batch), block 256 (4 waves x 16 q-rows).
// chunk c covers keys s in [t0 + c*256, t0 + (c+1)*256) ∩ [t0, T).
__global__ __launch_bounds__(256) void attn_part(const unsigned short* __restrict__ Qb,
                                                 const unsigned short* __restrict__ Kb,
                                                 const unsigned short* __restrict__ vT,
                                                 float* __restrict__ mP,
                                                 float* __restrict__ lP,
                                                 float* __restrict__ oP) {
    int c  = blockIdx.x;
    int qt = blockIdx.y;
    int b  = blockIdx.z;
    int t0 = qt * 64;
    int sBeg = t0 + c * 256;
    if (sBeg >= T_) return;
    int sEnd = sBeg + 256; if (sEnd > T_) sEnd = T_;

    __shared__ unsigned short ks[64][72];
    __shared__ unsigned short vts[64][72];
    __shared__ unsigned short ps[4][16][72];

    int tid  = threadIdx.x;
    int lane = tid & 63, wv = tid >> 6;
    int lrow = lane & 15;
    int lk   = (lane >> 4) * 8;
    int qrow4 = (lane >> 4) * 4;
    int sr = tid >> 2, sc = tid & 3;

    bf16x8 qf[2];
    {
        const unsigned short* qp = Qb + (size_t)(b * T_ + t0 + wv * 16 + lrow) * 64 + lk;
        qf[0] = *(const bf16x8*)(qp);
        qf[1] = *(const bf16x8*)(qp + 32);
    }

    float m_[4], l_[4];
    floatx4 of[4] = {};
    #pragma unroll
    for (int rg = 0; rg < 4; ++rg) { m_[rg] = -__builtin_inff(); l_[rg] = 0.f; }

    for (int s0 = sBeg; s0 < sEnd; s0 += 64) {
        {
            const ushort8* kp = (const ushort8*)(Kb + (size_t)(b * T_ + s0 + sr) * 64 + sc * 16);
            ushort8 k0v = kp[0], k1v = kp[1];
            *(ushort8*)&ks[sr][sc * 16]     = k0v;
            *(ushort8*)&ks[sr][sc * 16 + 8] = k1v;
            const ushort8* vp = (const ushort8*)(vT + (size_t)(b * 64 + sr) * T_ + s0 + sc * 16);
            ushort8 v0v = vp[0], v1v = vp[1];
            *(ushort8*)&vts[sr][sc * 16]     = v0v;
            *(ushort8*)&vts[sr][sc * 16 + 8] = v1v;
        }
        __syncthreads();

        floatx4 sf[4] = {};
        #pragma unroll
        for (int kc = 0; kc < 2; ++kc) {
            bf16x8 af = qf[kc];
            #pragma unroll
            for (int nf = 0; nf < 4; ++nf) {
                bf16x8 bfv = *(const bf16x8*)&ks[nf * 16 + lrow][kc * 32 + lk];
                sf[nf] = __builtin_amdgcn_mfma_f32_16x16x32_bf16(af, bfv, sf[nf], 0, 0, 0);
            }
        }

        if (s0 == t0) {   // diagonal tile: key s < query t -> -inf
            #pragma unroll
            for (int nf = 0; nf < 4; ++nf)
                #pragma unroll
                for (int rg = 0; rg < 4; ++rg) {
                    int sl = nf * 16 + lrow;
                    int ql = wv * 16 + qrow4 + rg;
                    if (sl < ql) sf[nf][rg] = -__builtin_inff();
                }
        }

        float alpha[4];
        #pragma unroll
        for (int rg = 0; rg < 4; ++rg) {
            float v = fmaxf(fmaxf(sf[0][rg], sf[1][rg]), fmaxf(sf[2][rg], sf[3][rg]));
            v = fmaxf(v, __shfl_xor(v, 1, 64));
            v = fmaxf(v, __shfl_xor(v, 2, 64));
            v = fmaxf(v, __shfl_xor(v, 4, 64));
            v = fmaxf(v, __shfl_xor(v, 8, 64));
            float mn = fmaxf(m_[rg], v);
            alpha[rg] = exp2f(m_[rg] - mn);
            m_[rg] = mn;
            l_[rg] *= alpha[rg];
        }

        #pragma unroll
        for (int nf = 0; nf < 4; ++nf)
            #pragma unroll
            for (int rg = 0; rg < 4; ++rg) {
                float p = exp2f(sf[nf][rg] - m_[rg]);
                l_[rg] += p;
                ps[wv][qrow4 + rg][nf * 16 + lrow] = f2bf(p);
            }

        #pragma unroll
        for (int hf = 0; hf < 4; ++hf)
            #pragma unroll
            for (int rg = 0; rg < 4; ++rg)
                of[hf][rg] *= alpha[rg];

        #pragma unroll
        for (int kc = 0; kc < 2; ++kc) {
            bf16x8 pa = *(const bf16x8*)&ps[wv][lrow][kc * 32 + lk];
            #pragma unroll
            for (int hf = 0; hf < 4; ++hf) {
                bf16x8 vbv = *(const bf16x8*)&vts[hf * 16 + lrow][kc * 32 + lk];
                of[hf] = __builtin_amdgcn_mfma_f32_16x16x32_bf16(pa, vbv, of[hf], 0, 0, 0);
            }
        }
        __syncthreads();
    }

    // epilogue: store unnormalized partials
    int p = (b * 32 + qt) * 8 + c;
    #pragma unroll
    for (int rg = 0; rg < 4; ++rg) {
        float v = l_[rg];
        v += __shfl_xor(v, 1, 64);
        v += __shfl_xor(v, 2, 64);
        v += __shfl_xor(v, 4, 64);
        v += __shfl_xor(v, 8, 64);
        l_[rg] = v;
    }
    if (lrow == 0) {
        #pragma unroll
        for (int rg = 0; rg < 4; ++rg) {
            int row = wv * 16 + qrow4 + rg;
            mP[(size_t)p * 64 + row] = m_[rg];
            lP[(size_t)p * 64 + row] = l_[rg];
        }
    }
    #pragma unroll
    for (int hf = 0; hf < 4; ++hf)
        #pragma unroll
        for (int rg = 0; rg < 4; ++rg) {
            int row = wv * 16 + qrow4 + rg;
            oP[((size_t)p * 64 + row) * 64 + hf * 16 + lrow] = of[hf][rg];
        }
}

// ---------------- kernel 3: combine partials ----------------
__global__ __launch_bounds__(256) void combine(const float* __restrict__ mP,
                                               const float* __restrict__ lP,
                                               const float* __restrict__ oP,
                                               float* __restrict__ out) {
    int bq = blockIdx.x >> 2;       // 0..127 = b*32+qt
    int rq = blockIdx.x & 3;
    int qt = bq & 31;
    int b  = bq >> 5;
    int nch = (32 - qt + 3) >> 2;

    int tid = threadIdx.x;
    int r   = rq * 16 + (tid >> 4);
    int cb  = (tid & 15) * 4;

    float M = -__builtin_inff();
    for (int cc = 0; cc < nch; ++cc)
        M = fmaxf(M, mP[(size_t)(bq * 8 + cc) * 64 + r]);

    float L = 0.f;
    float4 o = {0.f, 0.f, 0.f, 0.f};
    for (int cc = 0; cc < nch; ++cc) {
        size_t p = (size_t)(bq * 8 + cc);
        float w = exp2f(mP[p * 64 + r] - M);
        L += lP[p * 64 + r] * w;
        float4 ov = *(const float4*)&oP[(p * 64 + r) * 64 + cb];
        o.x += ov.x * w; o.y += ov.y * w; o.z += ov.z * w; o.w += ov.w * w;
    }
    float inv = 1.0f / L;
    float4 res = {o.x * inv, o.y * inv, o.z * inv, o.w * inv};
    *(float4*)&out[((size_t)(b * T_ + qt * 64 + r)) * 64 + cb] = res;
}

extern "C" void kernel_launch(void* const* d_in, const int* in_sizes, int n_in,
                              void* d_out, int out_size, void* d_ws, size_t ws_size,
                              hipStream_t stream) {
    const float* x  = (const float*)d_in[0];
    const float* Wq = (const float*)d_in[1];
    const float* Wk = (const float*)d_in[2];
    const float* Wv = (const float*)d_in[3];
    float* out = (float*)d_out;

    unsigned short* wT = (unsigned short*)d_ws;       // 288 KB
    unsigned short* Qb = wT + 3 * 64 * 768;           // 1 MB
    unsigned short* Kb = Qb + 8192 * 64;              // 1 MB
    unsigned short* vT = Kb + 8192 * 64;              // 1 MB  [b][h][t]
    float* mP = (float*)(vT + 4 * 64 * T_);           // 256 KB
    float* lP = mP + 1024 * 64;                       // 256 KB
    float* oP = lP + 1024 * 64;                       // 16.75 MB

    prep_wT<<<36, 256, 0, stream>>>(Wq, Wk, Wv, wT);
    qkv_proj<<<512, 256, 0, stream>>>(x, wT, Qb, Kb, vT);
    attn_part<<<dim3(8, 32, 4), 256, 0, stream>>>(Qb, Kb, vT, mP, lP, oP);
    combine<<<512, 256, 0, stream>>>(mP, lP, oP, out);
}